// Round 1
// baseline (972.365 us; speedup 1.0000x reference)
//
#include <hip/hip_runtime.h>
#include <math.h>

#define NHALF 4096
#define NTOT  8192
#define DIN   512
#define DF    64      // padded deep-feature dim (50 real + 14 zeros)
#define BK    32
#define LDT   132     // padded LDS tile leading dim

__device__ __forceinline__ float softplus_f(float x) {
    return fmaxf(x, 0.f) + log1pf(expf(-fabsf(x)));
}

// ---------------- Kernel A: featurize + norms ----------------
// one wave per row; 2048 blocks x 256 threads
__global__ __launch_bounds__(256) void featurize_kernel(
    const float* __restrict__ Xs, const float* __restrict__ Xt,
    const float* __restrict__ W1, const float* __restrict__ b1,
    const float* __restrict__ W2, const float* __restrict__ b2,
    const float* __restrict__ W3, const float* __restrict__ b3,
    const float* __restrict__ W4, const float* __restrict__ b4,
    float* __restrict__ Fea, float* __restrict__ norm_org, float* __restrict__ norm_fea)
{
    int row  = (blockIdx.x * blockDim.x + threadIdx.x) >> 6;
    int lane = threadIdx.x & 63;
    if (row >= NTOT) return;
    const float* src = (row < NHALF) ? (Xs + (size_t)row * DIN)
                                     : (Xt + (size_t)(row - NHALF) * DIN);
    float4 v0 = ((const float4*)src)[lane * 2];
    float4 v1 = ((const float4*)src)[lane * 2 + 1];
    float x[8] = {v0.x, v0.y, v0.z, v0.w, v1.x, v1.y, v1.z, v1.w};

    float p[10];
#pragma unroll
    for (int j = 0; j < 10; ++j) p[j] = 0.f;
    float on = 0.f;
    int ibase = lane * 8;
#pragma unroll
    for (int t = 0; t < 8; ++t) {
        float xv = x[t];
        on += xv * xv;
        const float* wrow = W1 + (size_t)(ibase + t) * 10;
#pragma unroll
        for (int j = 0; j < 10; ++j) p[j] = fmaf(xv, wrow[j], p[j]);
    }
#pragma unroll
    for (int m = 32; m >= 1; m >>= 1) {
#pragma unroll
        for (int j = 0; j < 10; ++j) p[j] += __shfl_xor(p[j], m, 64);
        on += __shfl_xor(on, m, 64);
    }
    // all lanes now hold full h1 pre-activation sums
    float h[10], h2[10];
#pragma unroll
    for (int j = 0; j < 10; ++j) h[j] = softplus_f(p[j] + b1[j]);
#pragma unroll
    for (int j = 0; j < 10; ++j) {
        float a = b2[j];
#pragma unroll
        for (int k = 0; k < 10; ++k) a = fmaf(h[k], W2[k * 10 + j], a);
        h2[j] = softplus_f(a);
    }
#pragma unroll
    for (int j = 0; j < 10; ++j) {
        float a = b3[j];
#pragma unroll
        for (int k = 0; k < 10; ++k) a = fmaf(h2[k], W3[k * 10 + j], a);
        h[j] = softplus_f(a);
    }
    float o = 0.f;
    if (lane < 50) {
        float a = b4[lane];
#pragma unroll
        for (int k = 0; k < 10; ++k) a = fmaf(h[k], W4[k * 50 + lane], a);
        o = a;
    }
    Fea[(size_t)row * DF + lane] = o;
    float fn = o * o;
#pragma unroll
    for (int m = 32; m >= 1; m >>= 1) fn += __shfl_xor(fn, m, 64);
    if (lane == 0) { norm_org[row] = on; norm_fea[row] = fn; }
}

// ---------------- Kernel B: trace(Kxy) ----------------
// one wave per diagonal pair; 1024 blocks x 256 threads
__global__ __launch_bounds__(256) void trace_kernel(
    const float* __restrict__ Xs, const float* __restrict__ Xt,
    const float* __restrict__ Fea,
    const float* __restrict__ epsP, const float* __restrict__ sigP,
    const float* __restrict__ sig0P,
    double* __restrict__ partialsB)
{
    int wib  = threadIdx.x >> 6;
    int lane = threadIdx.x & 63;
    int p = blockIdx.x * 4 + wib;  // 0..4095
    float ep = 1.f / (1.f + expf(-epsP[0]));
    float s = sigP[0], s0 = sig0P[0];
    float inv_s  = 1.f / (s * s);
    float inv_s0 = 1.f / (s0 * s0);

    const float4* a = (const float4*)(Xs + (size_t)p * DIN);
    const float4* b = (const float4*)(Xt + (size_t)p * DIN);
    float doo = 0.f;
#pragma unroll
    for (int t = 0; t < 2; ++t) {
        float4 av = a[lane * 2 + t], bv = b[lane * 2 + t];
        float dx = av.x - bv.x, dy = av.y - bv.y, dz = av.z - bv.z, dw = av.w - bv.w;
        doo += dx * dx + dy * dy + dz * dz + dw * dw;
    }
    float fi = Fea[(size_t)p * DF + lane];
    float fj = Fea[(size_t)(p + NHALF) * DF + lane];
    float d = fi - fj;
    float dd = d * d;
#pragma unroll
    for (int m = 32; m >= 1; m >>= 1) {
        doo += __shfl_xor(doo, m, 64);
        dd  += __shfl_xor(dd, m, 64);
    }
    float eo = __expf(-doo * inv_s);
    float K = (1.f - ep) * __expf(-dd * inv_s0) * eo + ep * eo;

    __shared__ double sred[4];
    if (lane == 0) sred[wib] = (double)K;
    __syncthreads();
    if (threadIdx.x == 0) partialsB[blockIdx.x] = sred[0] + sred[1] + sred[2] + sred[3];
}

// ---------------- Kernel C: fused pairwise dual-GEMM + kernel eval ----------------
__device__ __forceinline__ void stage_tile(float dst[BK][LDT], const float* __restrict__ src,
                                           int ld, int k0, int tid)
{
    int r  = tid >> 3;   // 0..31
    int c4 = tid & 7;    // float4 column within 32-wide K chunk
    const float* s0 = src + k0 + c4 * 4;
#pragma unroll
    for (int rr = 0; rr < 4; ++rr) {
        int row = rr * 32 + r;
        const float4 v = *(const float4*)(s0 + (size_t)row * ld);
        dst[c4 * 4 + 0][row] = v.x;
        dst[c4 * 4 + 1][row] = v.y;
        dst[c4 * 4 + 2][row] = v.z;
        dst[c4 * 4 + 3][row] = v.w;
    }
}

__device__ __forceinline__ void compute_tile(float acc[8][8],
                                             const float As[BK][LDT],
                                             const float Bs[BK][LDT],
                                             int tx, int ty)
{
#pragma unroll 4
    for (int k = 0; k < BK; ++k) {
        float a[8], b[8];
        *(float4*)&a[0] = *(const float4*)&As[k][ty * 8];
        *(float4*)&a[4] = *(const float4*)&As[k][ty * 8 + 4];
        *(float4*)&b[0] = *(const float4*)&Bs[k][tx * 8];
        *(float4*)&b[4] = *(const float4*)&Bs[k][tx * 8 + 4];
#pragma unroll
        for (int i = 0; i < 8; ++i)
#pragma unroll
            for (int j = 0; j < 8; ++j)
                acc[i][j] = fmaf(a[i], b[j], acc[i][j]);
    }
}

__global__ __launch_bounds__(256, 2) void pairwise_kernel(
    const float* __restrict__ Xs, const float* __restrict__ Xt,
    const float* __restrict__ Fea,
    const float* __restrict__ norm_org, const float* __restrict__ norm_fea,
    const float* __restrict__ epsP, const float* __restrict__ sigP,
    const float* __restrict__ sig0P,
    double* __restrict__ partialsC)
{
    __shared__ float As[BK][LDT];
    __shared__ float Bs[BK][LDT];
    __shared__ double sredC[4];

    int bi = blockIdx.y, bj = blockIdx.x;
    int tid = threadIdx.x;
    int tx = tid & 15, ty = tid >> 4;

    int row0_i = bi * 128, row0_j = bj * 128;
    const float* Abase = (row0_i < NHALF) ? (Xs + (size_t)row0_i * DIN)
                                          : (Xt + (size_t)(row0_i - NHALF) * DIN);
    const float* Bbase = (row0_j < NHALF) ? (Xs + (size_t)row0_j * DIN)
                                          : (Xt + (size_t)(row0_j - NHALF) * DIN);
    const float* FA = Fea + (size_t)row0_i * DF;
    const float* FB = Fea + (size_t)row0_j * DF;

    float acc1[8][8] = {};
    float acc2[8][8] = {};

    // main distance GEMM over K=512
    for (int kk = 0; kk < DIN / BK; ++kk) {
        stage_tile(As, Abase, DIN, kk * BK, tid);
        stage_tile(Bs, Bbase, DIN, kk * BK, tid);
        __syncthreads();
        compute_tile(acc1, As, Bs, tx, ty);
        __syncthreads();
    }
    // deep-feature GEMM over K=64 (padded)
    for (int kk = 0; kk < DF / BK; ++kk) {
        stage_tile(As, FA, DF, kk * BK, tid);
        stage_tile(Bs, FB, DF, kk * BK, tid);
        __syncthreads();
        compute_tile(acc2, As, Bs, tx, ty);
        __syncthreads();
    }

    // epilogue
    int gi0 = row0_i + ty * 8;
    int gj0 = row0_j + tx * 8;
    float oni[8], onj[8], fni[8], fnj[8];
#pragma unroll
    for (int i = 0; i < 8; ++i) { oni[i] = norm_org[gi0 + i]; fni[i] = norm_fea[gi0 + i]; }
#pragma unroll
    for (int j = 0; j < 8; ++j) { onj[j] = norm_org[gj0 + j]; fnj[j] = norm_fea[gj0 + j]; }

    float ep = 1.f / (1.f + expf(-epsP[0]));
    float s = sigP[0], s0 = sig0P[0];
    float inv_s  = 1.f / (s * s);
    float inv_s0 = 1.f / (s0 * s0);
    float sgn = ((gi0 < NHALF) == (gj0 < NHALF)) ? 1.f : -1.f;

    double loc = 0.0;
#pragma unroll
    for (int i = 0; i < 8; ++i) {
#pragma unroll
        for (int j = 0; j < 8; ++j) {
            float Do = fmaxf(fmaf(-2.f, acc1[i][j], oni[i] + onj[j]), 0.f);
            float Dd = fmaxf(fmaf(-2.f, acc2[i][j], fni[i] + fnj[j]), 0.f);
            float eo = __expf(-Do * inv_s);
            float K = (1.f - ep) * __expf(-Dd * inv_s0) * eo + ep * eo;
            if (gi0 + i == gj0 + j) K = 0.f;
            loc += (double)(sgn * K);
        }
    }
    // block-reduce the double
#pragma unroll
    for (int m = 32; m >= 1; m >>= 1) loc += __shfl_xor(loc, m, 64);
    if ((tid & 63) == 0) sredC[tid >> 6] = loc;
    __syncthreads();
    if (tid == 0)
        partialsC[(size_t)blockIdx.y * gridDim.x + blockIdx.x] =
            sredC[0] + sredC[1] + sredC[2] + sredC[3];
}

// ---------------- Kernel D: final reduce ----------------
__global__ __launch_bounds__(256) void reduce_kernel(
    const double* __restrict__ partialsC, const double* __restrict__ partialsB,
    float* __restrict__ out)
{
    double s = 0.0, t = 0.0;
    for (int i = threadIdx.x; i < 4096; i += 256) s += partialsC[i];
    for (int i = threadIdx.x; i < 1024; i += 256) t += partialsB[i];
#pragma unroll
    for (int m = 32; m >= 1; m >>= 1) {
        s += __shfl_xor(s, m, 64);
        t += __shfl_xor(t, m, 64);
    }
    __shared__ double ss[4], tt[4];
    int w = threadIdx.x >> 6;
    if ((threadIdx.x & 63) == 0) { ss[w] = s; tt[w] = t; }
    __syncthreads();
    if (threadIdx.x == 0) {
        double S = ss[0] + ss[1] + ss[2] + ss[3];
        double T = tt[0] + tt[1] + tt[2] + tt[3];
        out[0] = (float)((S + 2.0 * T) / (4096.0 * 4095.0));
    }
}

extern "C" void kernel_launch(void* const* d_in, const int* in_sizes, int n_in,
                              void* d_out, int out_size, void* d_ws, size_t ws_size,
                              hipStream_t stream)
{
    const float* Xs  = (const float*)d_in[0];
    const float* Xt  = (const float*)d_in[1];
    const float* W1  = (const float*)d_in[2];
    const float* b1  = (const float*)d_in[3];
    const float* W2  = (const float*)d_in[4];
    const float* b2  = (const float*)d_in[5];
    const float* W3  = (const float*)d_in[6];
    const float* b3  = (const float*)d_in[7];
    const float* W4  = (const float*)d_in[8];
    const float* b4  = (const float*)d_in[9];
    const float* epsP  = (const float*)d_in[10];
    const float* sigP  = (const float*)d_in[11];
    const float* sig0P = (const float*)d_in[12];
    float* out = (float*)d_out;

    char* ws = (char*)d_ws;
    float* Fea      = (float*)ws;             // 8192*64 floats
    float* norm_org = Fea + (size_t)NTOT * DF; // 8192
    float* norm_fea = norm_org + NTOT;         // 8192
    size_t fbytes = ((size_t)NTOT * DF + 2 * NTOT) * sizeof(float); // 2162688, 8-aligned
    double* partialsC = (double*)(ws + fbytes); // 4096
    double* partialsB = partialsC + 4096;       // 1024

    featurize_kernel<<<dim3(2048), dim3(256), 0, stream>>>(
        Xs, Xt, W1, b1, W2, b2, W3, b3, W4, b4, Fea, norm_org, norm_fea);
    trace_kernel<<<dim3(1024), dim3(256), 0, stream>>>(
        Xs, Xt, Fea, epsP, sigP, sig0P, partialsB);
    pairwise_kernel<<<dim3(64, 64), dim3(256), 0, stream>>>(
        Xs, Xt, Fea, norm_org, norm_fea, epsP, sigP, sig0P, partialsC);
    reduce_kernel<<<dim3(1), dim3(256), 0, stream>>>(partialsC, partialsB, out);
}

// Round 2
// 304.249 us; speedup vs baseline: 3.1960x; 3.1960x over previous
//
#include <hip/hip_runtime.h>
#include <math.h>

#define NHALF 4096
#define NTOT  8192
#define DIN   512
#define DF    64      // Fea row pitch (50 real + 14 zeros)
#define DFR   50      // real deep-feature dim
#define BM    128     // tile M = N
#define BK    32      // MFMA k-step
#define TPITCH 40     // bf16 pitch of staged X tiles (pad vs 32)
#define FPITCH 132    // f32 pitch of staged Ft tiles
#define KHALF 25      // Dd k staged in two halves

typedef short short8 __attribute__((ext_vector_type(8)));
typedef float f32x4 __attribute__((ext_vector_type(4)));

__device__ __forceinline__ float softplus_f(float x) {
    return fmaxf(x, 0.f) + log1pf(expf(-fabsf(x)));
}

__device__ __forceinline__ unsigned cvt_pk_bf16(float lo, float hi) {
    unsigned r;
    asm("v_cvt_pk_bf16_f32 %0, %1, %2" : "=v"(r) : "v"(lo), "v"(hi));
    return r;
}

// ---------------- Kernel A: featurize + norms ----------------
__global__ __launch_bounds__(256) void featurize_kernel(
    const float* __restrict__ Xs, const float* __restrict__ Xt,
    const float* __restrict__ W1, const float* __restrict__ b1,
    const float* __restrict__ W2, const float* __restrict__ b2,
    const float* __restrict__ W3, const float* __restrict__ b3,
    const float* __restrict__ W4, const float* __restrict__ b4,
    float* __restrict__ Fea, float* __restrict__ norm_org, float* __restrict__ norm_fea)
{
    int row  = (blockIdx.x * blockDim.x + threadIdx.x) >> 6;
    int lane = threadIdx.x & 63;
    if (row >= NTOT) return;
    const float* src = (row < NHALF) ? (Xs + (size_t)row * DIN)
                                     : (Xt + (size_t)(row - NHALF) * DIN);
    float4 v0 = ((const float4*)src)[lane * 2];
    float4 v1 = ((const float4*)src)[lane * 2 + 1];
    float x[8] = {v0.x, v0.y, v0.z, v0.w, v1.x, v1.y, v1.z, v1.w};

    float p[10];
#pragma unroll
    for (int j = 0; j < 10; ++j) p[j] = 0.f;
    float on = 0.f;
    int ibase = lane * 8;
#pragma unroll
    for (int t = 0; t < 8; ++t) {
        float xv = x[t];
        on += xv * xv;
        const float* wrow = W1 + (size_t)(ibase + t) * 10;
#pragma unroll
        for (int j = 0; j < 10; ++j) p[j] = fmaf(xv, wrow[j], p[j]);
    }
#pragma unroll
    for (int m = 32; m >= 1; m >>= 1) {
#pragma unroll
        for (int j = 0; j < 10; ++j) p[j] += __shfl_xor(p[j], m, 64);
        on += __shfl_xor(on, m, 64);
    }
    float h[10], h2[10];
#pragma unroll
    for (int j = 0; j < 10; ++j) h[j] = softplus_f(p[j] + b1[j]);
#pragma unroll
    for (int j = 0; j < 10; ++j) {
        float a = b2[j];
#pragma unroll
        for (int k = 0; k < 10; ++k) a = fmaf(h[k], W2[k * 10 + j], a);
        h2[j] = softplus_f(a);
    }
#pragma unroll
    for (int j = 0; j < 10; ++j) {
        float a = b3[j];
#pragma unroll
        for (int k = 0; k < 10; ++k) a = fmaf(h2[k], W3[k * 10 + j], a);
        h[j] = softplus_f(a);
    }
    float o = 0.f;
    if (lane < DFR) {
        float a = b4[lane];
#pragma unroll
        for (int k = 0; k < 10; ++k) a = fmaf(h[k], W4[k * 50 + lane], a);
        o = a;
    }
    Fea[(size_t)row * DF + lane] = o;
    float fn = o * o;
#pragma unroll
    for (int m = 32; m >= 1; m >>= 1) fn += __shfl_xor(fn, m, 64);
    if (lane == 0) { norm_org[row] = on; norm_fea[row] = fn; }
}

// ---------------- Kernel B: trace(Kxy) ----------------
__global__ __launch_bounds__(256) void trace_kernel(
    const float* __restrict__ Xs, const float* __restrict__ Xt,
    const float* __restrict__ Fea,
    const float* __restrict__ epsP, const float* __restrict__ sigP,
    const float* __restrict__ sig0P,
    double* __restrict__ partialsB)
{
    int wib  = threadIdx.x >> 6;
    int lane = threadIdx.x & 63;
    int p = blockIdx.x * 4 + wib;
    float ep = 1.f / (1.f + expf(-epsP[0]));
    float s = sigP[0], s0 = sig0P[0];
    float inv_s  = 1.f / (s * s);
    float inv_s0 = 1.f / (s0 * s0);

    const float4* a = (const float4*)(Xs + (size_t)p * DIN);
    const float4* b = (const float4*)(Xt + (size_t)p * DIN);
    float doo = 0.f;
#pragma unroll
    for (int t = 0; t < 2; ++t) {
        float4 av = a[lane * 2 + t], bv = b[lane * 2 + t];
        float dx = av.x - bv.x, dy = av.y - bv.y, dz = av.z - bv.z, dw = av.w - bv.w;
        doo += dx * dx + dy * dy + dz * dz + dw * dw;
    }
    float fi = Fea[(size_t)p * DF + lane];
    float fj = Fea[(size_t)(p + NHALF) * DF + lane];
    float d = fi - fj;
    float dd = d * d;
#pragma unroll
    for (int m = 32; m >= 1; m >>= 1) {
        doo += __shfl_xor(doo, m, 64);
        dd  += __shfl_xor(dd, m, 64);
    }
    float eo = __expf(-doo * inv_s);
    float K = (1.f - ep) * __expf(-dd * inv_s0) * eo + ep * eo;

    __shared__ double sred[4];
    if (lane == 0) sred[wib] = (double)K;
    __syncthreads();
    if (threadIdx.x == 0) partialsB[blockIdx.x] = sred[0] + sred[1] + sred[2] + sred[3];
}

// ---------------- Kernel C: fused MFMA(Do) + fp32(Dd) pairwise, upper-tri ----------------
__device__ __forceinline__ void stage_xtile(unsigned short* __restrict__ tile,
                                            const float* __restrict__ src,
                                            int k0, int tid)
{
    int r  = tid >> 1;
    int kh = tid & 1;
    const float4* s = (const float4*)(src + (size_t)r * DIN + k0 + kh * 16);
    float4 v0 = s[0], v1 = s[1], v2 = s[2], v3 = s[3];
    unsigned p0 = cvt_pk_bf16(v0.x, v0.y);
    unsigned p1 = cvt_pk_bf16(v0.z, v0.w);
    unsigned p2 = cvt_pk_bf16(v1.x, v1.y);
    unsigned p3 = cvt_pk_bf16(v1.z, v1.w);
    unsigned p4 = cvt_pk_bf16(v2.x, v2.y);
    unsigned p5 = cvt_pk_bf16(v2.z, v2.w);
    unsigned p6 = cvt_pk_bf16(v3.x, v3.y);
    unsigned p7 = cvt_pk_bf16(v3.z, v3.w);
    uint4* dst = (uint4*)(tile + (size_t)r * TPITCH + kh * 16);
    dst[0] = make_uint4(p0, p1, p2, p3);
    dst[1] = make_uint4(p4, p5, p6, p7);
}

__global__ __launch_bounds__(256, 2) void pairwise_kernel(
    const float* __restrict__ Xs, const float* __restrict__ Xt,
    const float* __restrict__ Fea,
    const float* __restrict__ norm_org, const float* __restrict__ norm_fea,
    const float* __restrict__ epsP, const float* __restrict__ sigP,
    const float* __restrict__ sig0P,
    double* __restrict__ partialsC)
{
    __shared__ char smem[26432] __attribute__((aligned(16)));
    __shared__ double sredC[4];

    int bi = blockIdx.y, bj = blockIdx.x;
    int bid = bi * gridDim.x + bj;
    int tid = threadIdx.x;
    if (bj < bi) {                      // lower triangle: symmetric, skip
        if (tid == 0) partialsC[bid] = 0.0;
        return;
    }
    unsigned short* tA = (unsigned short*)smem;
    unsigned short* tB = (unsigned short*)(smem + 10240);
    float* FtA = (float*)smem;
    float* FtB = (float*)(smem + 13216);

    int lane = tid & 63, wave = tid >> 6;
    int g = lane >> 4, l15 = lane & 15;
    int i0w = (wave >> 1) * 64;         // wave 2x2 over the 128x128 tile
    int j0w = (wave & 1) * 64;
    int ri = bi * BM, rj = bj * BM;
    const float* XA = (ri < NHALF) ? (Xs + (size_t)ri * DIN) : (Xt + (size_t)(ri - NHALF) * DIN);
    const float* XB = (rj < NHALF) ? (Xs + (size_t)rj * DIN) : (Xt + (size_t)(rj - NHALF) * DIN);

    // ---- Phase 1: Do dot-products via bf16 MFMA over K=512 ----
    f32x4 acc[4][4];
#pragma unroll
    for (int a = 0; a < 4; ++a)
#pragma unroll
        for (int b = 0; b < 4; ++b) acc[a][b] = (f32x4){0.f, 0.f, 0.f, 0.f};

    for (int kk = 0; kk < DIN / BK; ++kk) {
        stage_xtile(tA, XA, kk * BK, tid);
        stage_xtile(tB, XB, kk * BK, tid);
        __syncthreads();
        short8 af[4], bfr[4];
#pragma unroll
        for (int a = 0; a < 4; ++a)
            af[a] = *(const short8*)(tA + (size_t)(i0w + 16 * a + l15) * TPITCH + g * 8);
#pragma unroll
        for (int b = 0; b < 4; ++b)
            bfr[b] = *(const short8*)(tB + (size_t)(j0w + 16 * b + l15) * TPITCH + g * 8);
#pragma unroll
        for (int a = 0; a < 4; ++a)
#pragma unroll
            for (int b = 0; b < 4; ++b)
                acc[a][b] = __builtin_amdgcn_mfma_f32_16x16x32_bf16(af[a], bfr[b], acc[a][b], 0, 0, 0);
        __syncthreads();
    }

    // ---- Phase 2: Dd dot-products in fp32, aligned to MFMA C layout ----
    // lane owns i = i0w+16a+4g+r (a,r in 0..3), j = j0w+16b+l15 (b in 0..3)
    float dd[16][4];
#pragma unroll
    for (int q = 0; q < 16; ++q)
#pragma unroll
        for (int b = 0; b < 4; ++b) dd[q][b] = 0.f;

    for (int h = 0; h < 2; ++h) {
        {   // stage transposed feature half-tiles Ft[k][row]
            int r = tid >> 1;
            int kpar = tid & 1;
            const float* fa = Fea + (size_t)(ri + r) * DF + h * KHALF;
            const float* fb = Fea + (size_t)(rj + r) * DF + h * KHALF;
#pragma unroll
            for (int kqi = 0; kqi < 13; ++kqi) {
                int kq = kpar + 2 * kqi;
                if (kq < KHALF) {
                    FtA[kq * FPITCH + r] = fa[kq];
                    FtB[kq * FPITCH + r] = fb[kq];
                }
            }
        }
        __syncthreads();
        for (int k = 0; k < KHALF; ++k) {
            f32x4 fa[4];
            float fj[4];
#pragma unroll
            for (int a = 0; a < 4; ++a)
                fa[a] = *(const f32x4*)(FtA + k * FPITCH + i0w + 16 * a + 4 * g);
#pragma unroll
            for (int b = 0; b < 4; ++b)
                fj[b] = FtB[k * FPITCH + j0w + 16 * b + l15];
#pragma unroll
            for (int a = 0; a < 4; ++a)
#pragma unroll
                for (int r = 0; r < 4; ++r) {
                    float fv = fa[a][r];
#pragma unroll
                    for (int b = 0; b < 4; ++b)
                        dd[a * 4 + r][b] = fmaf(fv, fj[b], dd[a * 4 + r][b]);
                }
        }
        __syncthreads();
    }

    // ---- Epilogue ----
    float oni[16], fni[16], onj[4], fnj[4];
#pragma unroll
    for (int a = 0; a < 4; ++a)
#pragma unroll
        for (int r = 0; r < 4; ++r) {
            int i = ri + i0w + 16 * a + 4 * g + r;
            oni[a * 4 + r] = norm_org[i];
            fni[a * 4 + r] = norm_fea[i];
        }
#pragma unroll
    for (int b = 0; b < 4; ++b) {
        int j = rj + j0w + 16 * b + l15;
        onj[b] = norm_org[j];
        fnj[b] = norm_fea[j];
    }
    float ep = 1.f / (1.f + expf(-epsP[0]));
    float s = sigP[0], s0 = sig0P[0];
    float inv_s  = 1.f / (s * s);
    float inv_s0 = 1.f / (s0 * s0);
    float sgn = ((ri < NHALF) == (rj < NHALF)) ? 1.f : -1.f;
    bool diag = (bi == bj);
    float wsgn = sgn * (diag ? 1.f : 2.f);

    double loc = 0.0;
#pragma unroll
    for (int a = 0; a < 4; ++a)
#pragma unroll
        for (int b = 0; b < 4; ++b)
#pragma unroll
            for (int r = 0; r < 4; ++r) {
                float Do = fmaxf(oni[a * 4 + r] + onj[b] - 2.f * acc[a][b][r], 0.f);
                float Dd = fmaxf(fni[a * 4 + r] + fnj[b] - 2.f * dd[a * 4 + r][b], 0.f);
                float eo = __expf(-Do * inv_s);
                float K = (1.f - ep) * __expf(-Dd * inv_s0) * eo + ep * eo;
                if (diag && (i0w + 16 * a + 4 * g + r == j0w + 16 * b + l15)) K = 0.f;
                loc += (double)(wsgn * K);
            }
#pragma unroll
    for (int m = 32; m >= 1; m >>= 1) loc += __shfl_xor(loc, m, 64);
    if (lane == 0) sredC[wave] = loc;
    __syncthreads();
    if (tid == 0)
        partialsC[bid] = sredC[0] + sredC[1] + sredC[2] + sredC[3];
}

// ---------------- Kernel D: final reduce ----------------
__global__ __launch_bounds__(256) void reduce_kernel(
    const double* __restrict__ partialsC, const double* __restrict__ partialsB,
    float* __restrict__ out)
{
    double s = 0.0, t = 0.0;
    for (int i = threadIdx.x; i < 4096; i += 256) s += partialsC[i];
    for (int i = threadIdx.x; i < 1024; i += 256) t += partialsB[i];
#pragma unroll
    for (int m = 32; m >= 1; m >>= 1) {
        s += __shfl_xor(s, m, 64);
        t += __shfl_xor(t, m, 64);
    }
    __shared__ double ss[4], tt[4];
    int w = threadIdx.x >> 6;
    if ((threadIdx.x & 63) == 0) { ss[w] = s; tt[w] = t; }
    __syncthreads();
    if (threadIdx.x == 0) {
        double S = ss[0] + ss[1] + ss[2] + ss[3];
        double T = tt[0] + tt[1] + tt[2] + tt[3];
        out[0] = (float)((S + 2.0 * T) / (4096.0 * 4095.0));
    }
}

extern "C" void kernel_launch(void* const* d_in, const int* in_sizes, int n_in,
                              void* d_out, int out_size, void* d_ws, size_t ws_size,
                              hipStream_t stream)
{
    const float* Xs  = (const float*)d_in[0];
    const float* Xt  = (const float*)d_in[1];
    const float* W1  = (const float*)d_in[2];
    const float* b1  = (const float*)d_in[3];
    const float* W2  = (const float*)d_in[4];
    const float* b2  = (const float*)d_in[5];
    const float* W3  = (const float*)d_in[6];
    const float* b3  = (const float*)d_in[7];
    const float* W4  = (const float*)d_in[8];
    const float* b4  = (const float*)d_in[9];
    const float* epsP  = (const float*)d_in[10];
    const float* sigP  = (const float*)d_in[11];
    const float* sig0P = (const float*)d_in[12];
    float* out = (float*)d_out;

    char* ws = (char*)d_ws;
    float* Fea      = (float*)ws;              // 8192*64 f32
    float* norm_org = Fea + (size_t)NTOT * DF; // 8192
    float* norm_fea = norm_org + NTOT;         // 8192
    size_t fbytes = ((size_t)NTOT * DF + 2 * NTOT) * sizeof(float);
    double* partialsC = (double*)(ws + fbytes); // 4096
    double* partialsB = partialsC + 4096;       // 1024

    featurize_kernel<<<dim3(2048), dim3(256), 0, stream>>>(
        Xs, Xt, W1, b1, W2, b2, W3, b3, W4, b4, Fea, norm_org, norm_fea);
    trace_kernel<<<dim3(1024), dim3(256), 0, stream>>>(
        Xs, Xt, Fea, epsP, sigP, sig0P, partialsB);
    pairwise_kernel<<<dim3(64, 64), dim3(256), 0, stream>>>(
        Xs, Xt, Fea, norm_org, norm_fea, epsP, sigP, sig0P, partialsC);
    reduce_kernel<<<dim3(1), dim3(256), 0, stream>>>(partialsC, partialsB, out);
}

// Round 3
// 208.736 us; speedup vs baseline: 4.6583x; 1.4576x over previous
//
#include <hip/hip_runtime.h>
#include <math.h>

#define NHALF 4096
#define NTOT  8192
#define DIN   512
#define DF    64      // Fea row pitch (50 real + 14 zeros)
#define DFR   50      // real deep-feature dim
#define BM    128     // tile M = N
#define FPITCH 132    // f32 pitch of staged Ft tiles
#define KHALF 25      // Dd k staged in two halves
#define NBI   64      // 8192/128
#define NTRI  2080    // 64*65/2 upper-tri blocks

typedef short short8 __attribute__((ext_vector_type(8)));
typedef float f32x4 __attribute__((ext_vector_type(4)));

__device__ __forceinline__ float softplus_f(float x) {
    return fmaxf(x, 0.f) + log1pf(expf(-fabsf(x)));
}

__device__ __forceinline__ unsigned cvt_pk_bf16(float lo, float hi) {
    unsigned r;
    asm("v_cvt_pk_bf16_f32 %0, %1, %2" : "=v"(r) : "v"(lo), "v"(hi));
    return r;
}

__device__ __forceinline__ void gload_lds16(const void* g, void* l) {
    __builtin_amdgcn_global_load_lds(
        (const __attribute__((address_space(1))) void*)g,
        (__attribute__((address_space(3))) void*)l, 16, 0, 0);
}

// ---------------- Kernel A: featurize + norms + bf16 convert ----------------
__global__ __launch_bounds__(256) void featurize_kernel(
    const float* __restrict__ Xs, const float* __restrict__ Xt,
    const float* __restrict__ W1, const float* __restrict__ b1,
    const float* __restrict__ W2, const float* __restrict__ b2,
    const float* __restrict__ W3, const float* __restrict__ b3,
    const float* __restrict__ W4, const float* __restrict__ b4,
    float* __restrict__ Fea, float* __restrict__ norm_org, float* __restrict__ norm_fea,
    unsigned short* __restrict__ Xbf)
{
    int row  = (blockIdx.x * blockDim.x + threadIdx.x) >> 6;
    int lane = threadIdx.x & 63;
    if (row >= NTOT) return;
    const float* src = (row < NHALF) ? (Xs + (size_t)row * DIN)
                                     : (Xt + (size_t)(row - NHALF) * DIN);
    float4 v0 = ((const float4*)src)[lane * 2];
    float4 v1 = ((const float4*)src)[lane * 2 + 1];
    float x[8] = {v0.x, v0.y, v0.z, v0.w, v1.x, v1.y, v1.z, v1.w};

    // bf16 copy (concatenated layout)
    unsigned q0 = cvt_pk_bf16(x[0], x[1]);
    unsigned q1 = cvt_pk_bf16(x[2], x[3]);
    unsigned q2 = cvt_pk_bf16(x[4], x[5]);
    unsigned q3 = cvt_pk_bf16(x[6], x[7]);
    *(uint4*)(Xbf + (size_t)row * DIN + lane * 8) = make_uint4(q0, q1, q2, q3);

    float p[10];
#pragma unroll
    for (int j = 0; j < 10; ++j) p[j] = 0.f;
    float on = 0.f;
    int ibase = lane * 8;
#pragma unroll
    for (int t = 0; t < 8; ++t) {
        float xv = x[t];
        on += xv * xv;
        const float* wrow = W1 + (size_t)(ibase + t) * 10;
#pragma unroll
        for (int j = 0; j < 10; ++j) p[j] = fmaf(xv, wrow[j], p[j]);
    }
#pragma unroll
    for (int m = 32; m >= 1; m >>= 1) {
#pragma unroll
        for (int j = 0; j < 10; ++j) p[j] += __shfl_xor(p[j], m, 64);
        on += __shfl_xor(on, m, 64);
    }
    float h[10], h2[10];
#pragma unroll
    for (int j = 0; j < 10; ++j) h[j] = softplus_f(p[j] + b1[j]);
#pragma unroll
    for (int j = 0; j < 10; ++j) {
        float a = b2[j];
#pragma unroll
        for (int k = 0; k < 10; ++k) a = fmaf(h[k], W2[k * 10 + j], a);
        h2[j] = softplus_f(a);
    }
#pragma unroll
    for (int j = 0; j < 10; ++j) {
        float a = b3[j];
#pragma unroll
        for (int k = 0; k < 10; ++k) a = fmaf(h2[k], W3[k * 10 + j], a);
        h[j] = softplus_f(a);
    }
    float o = 0.f;
    if (lane < DFR) {
        float a = b4[lane];
#pragma unroll
        for (int k = 0; k < 10; ++k) a = fmaf(h[k], W4[k * 50 + lane], a);
        o = a;
    }
    Fea[(size_t)row * DF + lane] = o;
    float fn = o * o;
#pragma unroll
    for (int m = 32; m >= 1; m >>= 1) fn += __shfl_xor(fn, m, 64);
    if (lane == 0) { norm_org[row] = on; norm_fea[row] = fn; }
}

// ---------------- Kernel B: trace(Kxy) ----------------
__global__ __launch_bounds__(256) void trace_kernel(
    const float* __restrict__ Xs, const float* __restrict__ Xt,
    const float* __restrict__ Fea,
    const float* __restrict__ epsP, const float* __restrict__ sigP,
    const float* __restrict__ sig0P,
    double* __restrict__ partialsB)
{
    int wib  = threadIdx.x >> 6;
    int lane = threadIdx.x & 63;
    int p = blockIdx.x * 4 + wib;
    float ep = 1.f / (1.f + expf(-epsP[0]));
    float s = sigP[0], s0 = sig0P[0];
    float inv_s  = 1.f / (s * s);
    float inv_s0 = 1.f / (s0 * s0);

    const float4* a = (const float4*)(Xs + (size_t)p * DIN);
    const float4* b = (const float4*)(Xt + (size_t)p * DIN);
    float doo = 0.f;
#pragma unroll
    for (int t = 0; t < 2; ++t) {
        float4 av = a[lane * 2 + t], bv = b[lane * 2 + t];
        float dx = av.x - bv.x, dy = av.y - bv.y, dz = av.z - bv.z, dw = av.w - bv.w;
        doo += dx * dx + dy * dy + dz * dz + dw * dw;
    }
    float fi = Fea[(size_t)p * DF + lane];
    float fj = Fea[(size_t)(p + NHALF) * DF + lane];
    float d = fi - fj;
    float dd = d * d;
#pragma unroll
    for (int m = 32; m >= 1; m >>= 1) {
        doo += __shfl_xor(doo, m, 64);
        dd  += __shfl_xor(dd, m, 64);
    }
    float eo = __expf(-doo * inv_s);
    float K = (1.f - ep) * __expf(-dd * inv_s0) * eo + ep * eo;

    __shared__ double sred[4];
    if (lane == 0) sred[wib] = (double)K;
    __syncthreads();
    if (threadIdx.x == 0) partialsB[blockIdx.x] = sred[0] + sred[1] + sred[2] + sred[3];
}

// ---------------- Kernel C: fused MFMA(Do) + fp32(Dd) pairwise, upper-tri ----------------
// LDS: 2 double-buffers x (A-tile 8KB + B-tile 8KB) = 32 KB, reused by phase 2.
__global__ __launch_bounds__(256, 2) void pairwise_kernel(
    const unsigned short* __restrict__ Xbf,
    const float* __restrict__ Fea,
    const float* __restrict__ norm_org, const float* __restrict__ norm_fea,
    const float* __restrict__ epsP, const float* __restrict__ sigP,
    const float* __restrict__ sig0P,
    double* __restrict__ partialsC)
{
    __shared__ char smem[32768] __attribute__((aligned(128)));
    __shared__ double sredC[4];

    int bid = blockIdx.x;
    // triangular decode: bi <= bj
    int bi = (int)((129.0 - sqrt(16641.0 - 8.0 * (double)bid)) * 0.5);
    while (NBI * (bi + 1) - (bi + 1) * bi / 2 <= bid) ++bi;
    while (NBI * bi - bi * (bi - 1) / 2 > bid) --bi;
    int bj = bi + (bid - (NBI * bi - bi * (bi - 1) / 2));

    int tid = threadIdx.x;
    int lane = tid & 63, wave = tid >> 6;
    int g = lane >> 4, l15 = lane & 15;
    int i0w = (wave >> 1) * 64;
    int j0w = (wave & 1) * 64;
    int ri = bi * BM, rj = bj * BM;

    // staging source addresses (lane-constant except kk*64 bytes)
    int srow = tid >> 2;                             // row within a 64-row issue
    int schunk = (tid & 3) ^ ((srow >> 1) & 3);      // inverse-swizzled source chunk
    const char* sA0 = (const char*)(Xbf + (size_t)(ri + srow) * DIN + schunk * 8);
    const char* sB0 = (const char*)(Xbf + (size_t)(rj + srow) * DIN + schunk * 8);
    char* lbase = (char*)smem + wave * 1024;         // wave-uniform

    // fragment read offsets (swizzled): row pitch 32 shorts, chunk 8 shorts
    int swz = (l15 >> 1) & 3;
    int offA = (i0w + l15) * 32 + (g ^ swz) * 8;
    int offB = (j0w + l15) * 32 + (g ^ swz) * 8;

    f32x4 acc[4][4];
#pragma unroll
    for (int a = 0; a < 4; ++a)
#pragma unroll
        for (int b = 0; b < 4; ++b) acc[a][b] = (f32x4){0.f, 0.f, 0.f, 0.f};

    // ---- Phase 1: Do via bf16 MFMA over K=512, double-buffered gload_lds ----
    {
        // prologue: stage k-iter 0 into buffer 0
        gload_lds16(sA0,          lbase);
        gload_lds16(sA0 + 65536,  lbase + 4096);
        gload_lds16(sB0,          lbase + 8192);
        gload_lds16(sB0 + 65536,  lbase + 12288);
        __syncthreads();

        for (int kk = 0; kk < 16; ++kk) {
            int cur = kk & 1;
            if (kk < 15) {
                const char* gA = sA0 + (kk + 1) * 64;
                const char* gB = sB0 + (kk + 1) * 64;
                char* ld = lbase + (cur ^ 1) * 16384;
                gload_lds16(gA,         ld);
                gload_lds16(gA + 65536, ld + 4096);
                gload_lds16(gB,         ld + 8192);
                gload_lds16(gB + 65536, ld + 12288);
            }
            const unsigned short* tc = (const unsigned short*)(smem + cur * 16384);
            short8 af[4], bfr[4];
#pragma unroll
            for (int a = 0; a < 4; ++a)
                af[a] = *(const short8*)(tc + offA + a * 512);
#pragma unroll
            for (int b = 0; b < 4; ++b)
                bfr[b] = *(const short8*)(tc + 4096 + offB + b * 512);
#pragma unroll
            for (int a = 0; a < 4; ++a)
#pragma unroll
                for (int b = 0; b < 4; ++b)
                    acc[a][b] = __builtin_amdgcn_mfma_f32_16x16x32_bf16(af[a], bfr[b], acc[a][b], 0, 0, 0);
            __syncthreads();   // drains vmcnt (stage landed) + all reads of buf[cur] done
        }
    }

    // ---- Phase 2: Dd in fp32, aligned to MFMA C layout ----
    float* FtA = (float*)smem;
    float* FtB = (float*)(smem + 13216);
    float dd[16][4];
#pragma unroll
    for (int q = 0; q < 16; ++q)
#pragma unroll
        for (int b = 0; b < 4; ++b) dd[q][b] = 0.f;

    for (int h = 0; h < 2; ++h) {
        {   // stage transposed feature half-tiles Ft[k][row]
            int r = tid >> 1;
            int kpar = tid & 1;
            const float* fa = Fea + (size_t)(ri + r) * DF + h * KHALF;
            const float* fb = Fea + (size_t)(rj + r) * DF + h * KHALF;
#pragma unroll
            for (int kqi = 0; kqi < 13; ++kqi) {
                int kq = kpar + 2 * kqi;
                if (kq < KHALF) {
                    FtA[kq * FPITCH + r] = fa[kq];
                    FtB[kq * FPITCH + r] = fb[kq];
                }
            }
        }
        __syncthreads();
        for (int k = 0; k < KHALF; ++k) {
            f32x4 fa[4];
            float fj[4];
#pragma unroll
            for (int a = 0; a < 4; ++a)
                fa[a] = *(const f32x4*)(FtA + k * FPITCH + i0w + 16 * a + 4 * g);
#pragma unroll
            for (int b = 0; b < 4; ++b)
                fj[b] = FtB[k * FPITCH + j0w + 16 * b + l15];
#pragma unroll
            for (int a = 0; a < 4; ++a)
#pragma unroll
                for (int r = 0; r < 4; ++r) {
                    float fv = fa[a][r];
#pragma unroll
                    for (int b = 0; b < 4; ++b)
                        dd[a * 4 + r][b] = fmaf(fv, fj[b], dd[a * 4 + r][b]);
                }
        }
        __syncthreads();
    }

    // ---- Epilogue ----
    float oni[16], fni[16], onj[4], fnj[4];
#pragma unroll
    for (int a = 0; a < 4; ++a)
#pragma unroll
        for (int r = 0; r < 4; ++r) {
            int i = ri + i0w + 16 * a + 4 * g + r;
            oni[a * 4 + r] = norm_org[i];
            fni[a * 4 + r] = norm_fea[i];
        }
#pragma unroll
    for (int b = 0; b < 4; ++b) {
        int j = rj + j0w + 16 * b + l15;
        onj[b] = norm_org[j];
        fnj[b] = norm_fea[j];
    }
    float ep = 1.f / (1.f + expf(-epsP[0]));
    float s = sigP[0], s0 = sig0P[0];
    float inv_s  = 1.f / (s * s);
    float inv_s0 = 1.f / (s0 * s0);
    float sgn = ((ri < NHALF) == (rj < NHALF)) ? 1.f : -1.f;
    bool diag = (bi == bj);
    float wsgn = sgn * (diag ? 1.f : 2.f);

    double loc = 0.0;
#pragma unroll
    for (int a = 0; a < 4; ++a)
#pragma unroll
        for (int b = 0; b < 4; ++b)
#pragma unroll
            for (int r = 0; r < 4; ++r) {
                float Do = fmaxf(oni[a * 4 + r] + onj[b] - 2.f * acc[a][b][r], 0.f);
                float Dd = fmaxf(fni[a * 4 + r] + fnj[b] - 2.f * dd[a * 4 + r][b], 0.f);
                float eo = __expf(-Do * inv_s);
                float K = (1.f - ep) * __expf(-Dd * inv_s0) * eo + ep * eo;
                if (diag && (i0w + 16 * a + 4 * g + r == j0w + 16 * b + l15)) K = 0.f;
                loc += (double)(wsgn * K);
            }
#pragma unroll
    for (int m = 32; m >= 1; m >>= 1) loc += __shfl_xor(loc, m, 64);
    if (lane == 0) sredC[wave] = loc;
    __syncthreads();
    if (tid == 0)
        partialsC[bid] = sredC[0] + sredC[1] + sredC[2] + sredC[3];
}

// ---------------- Kernel D: final reduce ----------------
__global__ __launch_bounds__(256) void reduce_kernel(
    const double* __restrict__ partialsC, const double* __restrict__ partialsB,
    float* __restrict__ out)
{
    double s = 0.0, t = 0.0;
    for (int i = threadIdx.x; i < NTRI; i += 256) s += partialsC[i];
    for (int i = threadIdx.x; i < 1024; i += 256) t += partialsB[i];
#pragma unroll
    for (int m = 32; m >= 1; m >>= 1) {
        s += __shfl_xor(s, m, 64);
        t += __shfl_xor(t, m, 64);
    }
    __shared__ double ss[4], tt[4];
    int w = threadIdx.x >> 6;
    if ((threadIdx.x & 63) == 0) { ss[w] = s; tt[w] = t; }
    __syncthreads();
    if (threadIdx.x == 0) {
        double S = ss[0] + ss[1] + ss[2] + ss[3];
        double T = tt[0] + tt[1] + tt[2] + tt[3];
        out[0] = (float)((S + 2.0 * T) / (4096.0 * 4095.0));
    }
}

extern "C" void kernel_launch(void* const* d_in, const int* in_sizes, int n_in,
                              void* d_out, int out_size, void* d_ws, size_t ws_size,
                              hipStream_t stream)
{
    const float* Xs  = (const float*)d_in[0];
    const float* Xt  = (const float*)d_in[1];
    const float* W1  = (const float*)d_in[2];
    const float* b1  = (const float*)d_in[3];
    const float* W2  = (const float*)d_in[4];
    const float* b2  = (const float*)d_in[5];
    const float* W3  = (const float*)d_in[6];
    const float* b3  = (const float*)d_in[7];
    const float* W4  = (const float*)d_in[8];
    const float* b4  = (const float*)d_in[9];
    const float* epsP  = (const float*)d_in[10];
    const float* sigP  = (const float*)d_in[11];
    const float* sig0P = (const float*)d_in[12];
    float* out = (float*)d_out;

    char* ws = (char*)d_ws;
    unsigned short* Xbf = (unsigned short*)ws;                   // 8192*512 bf16 = 8 MB
    float* Fea      = (float*)(ws + (size_t)NTOT * DIN * 2);     // 8192*64 f32
    float* norm_org = Fea + (size_t)NTOT * DF;                   // 8192
    float* norm_fea = norm_org + NTOT;                           // 8192
    double* partialsC = (double*)(norm_fea + NTOT);              // 2080
    double* partialsB = partialsC + NTRI;                        // 1024

    featurize_kernel<<<dim3(2048), dim3(256), 0, stream>>>(
        Xs, Xt, W1, b1, W2, b2, W3, b3, W4, b4, Fea, norm_org, norm_fea, Xbf);
    trace_kernel<<<dim3(1024), dim3(256), 0, stream>>>(
        Xs, Xt, Fea, epsP, sigP, sig0P, partialsB);
    pairwise_kernel<<<dim3(NTRI), dim3(256), 0, stream>>>(
        Xbf, Fea, norm_org, norm_fea, epsP, sigP, sig0P, partialsC);
    reduce_kernel<<<dim3(1), dim3(256), 0, stream>>>(partialsC, partialsB, out);
}